// Round 12
// baseline (320.836 us; speedup 1.0000x reference)
//
#include <hip/hip_runtime.h>
#include <cstdint>
#include <cmath>

typedef __bf16 bf16;
typedef __bf16 bf16x8 __attribute__((ext_vector_type(8)));
typedef __bf16 bf16x4 __attribute__((ext_vector_type(4)));
typedef __bf16 bf16x2 __attribute__((ext_vector_type(2)));
typedef float  f32x4  __attribute__((ext_vector_type(4)));

#define B_   2
#define T_   2048
#define D_   1024
#define H_   16
#define HS_  64
#define NTOK (B_ * T_)   // 4096

// ---- async global->LDS, 16B per lane. LDS dest = wave-uniform base + lane*16.
typedef __attribute__((address_space(1))) uint8_t* gp1_t;
typedef __attribute__((address_space(3))) uint8_t* lp3_t;
__device__ __forceinline__ void gl_lds16(const void* g, void* l) {
    __builtin_amdgcn_global_load_lds((gp1_t)(uintptr_t)g,
                                     (lp3_t)(uint32_t)(uintptr_t)l,
                                     16, 0, 0);
}

__device__ __forceinline__ f32x4 mfma16(bf16x8 a, bf16x8 b, f32x4 c) {
    return __builtin_amdgcn_mfma_f32_16x16x32_bf16(a, b, c, 0, 0, 0);
}

// pack two f32 -> one dword of 2 bf16 via the HW packed convert
__device__ __forceinline__ uint32_t pk2(float lo, float hi) {
    uint32_t r;
    asm("v_cvt_pk_bf16_f32 %0, %1, %2" : "=v"(r) : "v"(lo), "v"(hi));
    return r;
}
// gfx950 two-register lane swaps: a[32:63] <-> b[0:31]
__device__ __forceinline__ void pl32(uint32_t& a, uint32_t& b) {
    asm("v_permlane32_swap_b32 %0, %1" : "+v"(a), "+v"(b));
}
// a[16:31] <-> b[0:15], a[48:63] <-> b[32:47]
__device__ __forceinline__ void pl16(uint32_t& a, uint32_t& b) {
    asm("v_permlane16_swap_b32 %0, %1" : "+v"(a), "+v"(b));
}

// =====================================================================
// prep_fused: ONE launch for all weight prep + ln1.
// =====================================================================
__global__ __launch_bounds__(256) void prep_fused(
    const float* __restrict__ Wq, const float* __restrict__ Wk,
    const float* __restrict__ Wv, const float* __restrict__ Wo,
    const float* __restrict__ W1, const float* __restrict__ W2,
    const float* __restrict__ x,  const float* __restrict__ g,
    const float* __restrict__ be,
    bf16* __restrict__ WqkvT, bf16* __restrict__ WoT,
    bf16* __restrict__ W1T,  bf16* __restrict__ W2T,
    bf16* __restrict__ hbuf) {
    const int bid = blockIdx.x;
    const int tid = threadIdx.x;

    if (bid >= 12288) {
        // ---------------- ln1: one row ----------------
        const int row = bid - 12288;
        const float4 v = ((const float4*)(x + (size_t)row * 1024))[tid];
        float s  = v.x + v.y + v.z + v.w;
        float s2 = v.x * v.x + v.y * v.y + v.z * v.z + v.w * v.w;
        for (int m = 1; m < 64; m <<= 1) {
            s  += __shfl_xor(s, m);
            s2 += __shfl_xor(s2, m);
        }
        __shared__ float rs[4], rq[4];
        const int lane = tid & 63, wv = tid >> 6;
        if (lane == 0) { rs[wv] = s; rq[wv] = s2; }
        __syncthreads();
        s  = rs[0] + rs[1] + rs[2] + rs[3];
        s2 = rq[0] + rq[1] + rq[2] + rq[3];
        const float mu   = s * (1.f / 1024.f);
        const float var  = s2 * (1.f / 1024.f) - mu * mu;
        const float rstd = rsqrtf(var + 1e-5f);
        const float4 gg = ((const float4*)g)[tid];
        const float4 bb = ((const float4*)be)[tid];
        bf16x4 o;
        o[0] = (bf16)((v.x - mu) * rstd * gg.x + bb.x);
        o[1] = (bf16)((v.y - mu) * rstd * gg.y + bb.y);
        o[2] = (bf16)((v.z - mu) * rstd * gg.z + bb.z);
        o[3] = (bf16)((v.w - mu) * rstd * gg.w + bb.w);
        *(bf16x4*)(hbuf + (size_t)row * 1024 + tid * 4) = o;
        return;
    }

    // ---------------- transpose-cast regions ----------------
    const float* in; bf16* out;
    int C, R, bx, by;
    if (bid < 3072) {              // qkv_pack: z-th head, R=1024, C=64
        const int z = bid >> 6, rem = bid & 63;
        bx = rem & 1; by = rem >> 1;
        C = HS_; R = D_;
        in  = (z < 16 ? Wq : z < 32 ? Wk : Wv) + (size_t)(z & 15) * D_ * HS_;
        out = WqkvT + (size_t)z * HS_ * D_;
    } else if (bid < 4096) {       // Wo: R=1024, C=1024
        const int rem = bid - 3072;
        bx = rem & 31; by = rem >> 5;
        C = 1024; R = 1024; in = Wo; out = WoT;
    } else if (bid < 8192) {       // W1: R=1024, C=4096
        const int rem = bid - 4096;
        bx = rem & 127; by = rem >> 7;
        C = 4096; R = 1024; in = W1; out = W1T;
    } else {                       // W2: R=4096, C=1024
        const int rem = bid - 8192;
        bx = rem & 31; by = rem >> 5;
        C = 1024; R = 4096; in = W2; out = W2T;
    }
    const int tx = tid & 31, ty = tid >> 5;
    const int c0 = bx * 32, r0 = by * 32;
    __shared__ float t[32][33];
    for (int i = 0; i < 4; i++) {
        int r = ty + i * 8;
        t[r][tx] = in[(size_t)(r0 + r) * C + c0 + tx];
    }
    __syncthreads();
    for (int i = 0; i < 4; i++) {
        int rr = ty + i * 8;
        out[(size_t)(c0 + rr) * R + r0 + tx] = (bf16)t[tx][rr];
    }
}

// =====================================================================
// LayerNorm: x [4096][1024] fp32 -> out bf16, one block per row (ln2)
// =====================================================================
__global__ __launch_bounds__(256) void ln_kernel(const float* __restrict__ x,
                                                 const float* __restrict__ g,
                                                 const float* __restrict__ b,
                                                 bf16* __restrict__ out) {
    const int row = blockIdx.x;
    const int tid = threadIdx.x;
    const float4 v = ((const float4*)(x + (size_t)row * 1024))[tid];
    float s  = v.x + v.y + v.z + v.w;
    float s2 = v.x * v.x + v.y * v.y + v.z * v.z + v.w * v.w;
    for (int m = 1; m < 64; m <<= 1) {
        s  += __shfl_xor(s, m);
        s2 += __shfl_xor(s2, m);
    }
    __shared__ float rs[4], rq[4];
    const int lane = tid & 63, wv = tid >> 6;
    if (lane == 0) { rs[wv] = s; rq[wv] = s2; }
    __syncthreads();
    s  = rs[0] + rs[1] + rs[2] + rs[3];
    s2 = rq[0] + rq[1] + rq[2] + rq[3];
    const float mu   = s * (1.f / 1024.f);
    const float var  = s2 * (1.f / 1024.f) - mu * mu;
    const float rstd = rsqrtf(var + 1e-5f);
    const float4 gg = ((const float4*)g)[tid];
    const float4 bb = ((const float4*)b)[tid];
    bf16x4 o;
    o[0] = (bf16)((v.x - mu) * rstd * gg.x + bb.x);
    o[1] = (bf16)((v.y - mu) * rstd * gg.y + bb.y);
    o[2] = (bf16)((v.z - mu) * rstd * gg.z + bb.z);
    o[3] = (bf16)((v.w - mu) * rstd * gg.w + bb.w);
    *(bf16x4*)(out + (size_t)row * 1024 + tid * 4) = o;
}

// out[i] = p0[i] + p1[i] + resid[i] + bias[i % 1024]  (float4 per thread)
__global__ __launch_bounds__(256) void combine2(const float* __restrict__ p0,
                                                const float* __restrict__ p1,
                                                const float* __restrict__ resid,
                                                const float* __restrict__ bias,
                                                float* __restrict__ out) {
    const int i4 = blockIdx.x * 256 + threadIdx.x;
    const float4 a = ((const float4*)p0)[i4];
    const float4 b = ((const float4*)p1)[i4];
    const float4 r = ((const float4*)resid)[i4];
    const float4 bb = ((const float4*)bias)[i4 & 255];
    float4 o;
    o.x = a.x + b.x + r.x + bb.x;
    o.y = a.y + b.y + r.y + bb.y;
    o.z = a.z + b.z + r.z + bb.z;
    o.w = a.w + b.w + r.w + bb.w;
    ((float4*)out)[i4] = o;
}

// =====================================================================
// gemm128v2: 128x128 tile, 256 threads (4 waves, 2M x 2N), minimal-sync
// ring-of-4 BK=32 subtile pipeline with counted vmcnt (4 loads/thread/
// subtile -> vmcnt 8/4/0). 64 KB LDS -> 2 blocks/CU. (QKV, Wo)
// =====================================================================
template <int BIAS, int RELU, int RES, int OUTBF16, int VTP = 0>
__global__ __launch_bounds__(256, 2) void gemm128v2(
    const bf16* __restrict__ A, const bf16* __restrict__ Bt,
    const float* __restrict__ bias, const float* __restrict__ resid,
    void* __restrict__ Cout, bf16* __restrict__ Vt, int M, int N, int K) {
    __shared__ __align__(16) bf16 Asub[4][128 * 32];
    __shared__ __align__(16) bf16 Bsub[4][128 * 32];
    const int tid  = threadIdx.x;
    const int lane = tid & 63, w = tid >> 6;          // 4 waves
    const int quad = lane >> 4, l15 = lane & 15;
    const int m0 = blockIdx.y * 128, n0 = blockIdx.x * 128;
    const int wm = (w & 1) * 64, wn = (w >> 1) * 64;
    const int S  = K / 32;

    const int slog = (((lane & 3) ^ ((lane >> 3) & 3)) * 8);
    const int crow = lane >> 2;
    const bf16* gA0 = A  + (size_t)(m0 + 32 * w + crow)      * K + slog;
    const bf16* gA1 = A  + (size_t)(m0 + 32 * w + 16 + crow) * K + slog;
    const bf16* gB0 = Bt + (size_t)(n0 + 32 * w + crow)      * K + slog;
    const bf16* gB1 = Bt + (size_t)(n0 + 32 * w + 16 + crow) * K + slog;

    for (int t = 0; t < 3; t++) {
        gl_lds16(gA0, &Asub[t][(32 * w) * 32]);
        gl_lds16(gA1, &Asub[t][(32 * w + 16) * 32]);
        gl_lds16(gB0, &Bsub[t][(32 * w) * 32]);
        gl_lds16(gB1, &Bsub[t][(32 * w + 16) * 32]);
        gA0 += 32; gA1 += 32; gB0 += 32; gB1 += 32;
    }

    f32x4 acc[4][4];
#pragma unroll
    for (int i = 0; i < 4; i++)
#pragma unroll
        for (int j = 0; j < 4; j++) acc[i][j] = f32x4{0.f, 0.f, 0.f, 0.f};

    const int swz = (quad ^ ((l15 >> 1) & 3)) * 8;
    const int aof = (wm + l15) * 32 + swz;   // + mi*512
    const int bof = (wn + l15) * 32 + swz;   // + ni*512

    asm volatile("s_waitcnt vmcnt(8)" ::: "memory");   // subtile 0 landed
    __builtin_amdgcn_sched_barrier(0);
    __builtin_amdgcn_s_barrier();

    for (int s = 0; s < S; s++) {
        const bf16* Ab = &Asub[s & 3][0];
        const bf16* Bb = &Bsub[s & 3][0];
        const int pb = (s + 3) & 3;
        bf16x8 af[4], bfr[4];
#pragma unroll
        for (int mi = 0; mi < 4; mi++) af[mi] = *(const bf16x8*)&Ab[aof + mi * 512];
#pragma unroll
        for (int ni = 0; ni < 4; ni++) bfr[ni] = *(const bf16x8*)&Bb[bof + ni * 512];
        if (s + 3 < S) {
            gl_lds16(gA0, &Asub[pb][(32 * w) * 32]);
            gl_lds16(gA1, &Asub[pb][(32 * w + 16) * 32]);
            gl_lds16(gB0, &Bsub[pb][(32 * w) * 32]);
            gl_lds16(gB1, &Bsub[pb][(32 * w + 16) * 32]);
            gA0 += 32; gA1 += 32; gB0 += 32; gB1 += 32;
        }
        asm volatile("s_waitcnt lgkmcnt(0)" ::: "memory");
        __builtin_amdgcn_sched_barrier(0);
        __builtin_amdgcn_s_setprio(1);
#pragma unroll
        for (int mi = 0; mi < 4; mi++)
#pragma unroll
            for (int ni = 0; ni < 4; ni++)
                acc[mi][ni] = mfma16(af[mi], bfr[ni], acc[mi][ni]);
        __builtin_amdgcn_s_setprio(0);
        __builtin_amdgcn_sched_barrier(0);
        if (s <= S - 4)      asm volatile("s_waitcnt vmcnt(8)" ::: "memory");
        else if (s == S - 3) asm volatile("s_waitcnt vmcnt(4)" ::: "memory");
        else if (s == S - 2) asm volatile("s_waitcnt vmcnt(0)" ::: "memory");
        __builtin_amdgcn_s_barrier();
    }

    // ================= epilogue =================
    for (int mi = 0; mi < 4; mi++) {
        for (int ni = 0; ni < 4; ni++) {
            const int colb = n0 + wn + ni * 16 + l15;
            if (VTP && colb >= 2048) {
                const int h = (colb - 2048) >> 6, hs = (colb - 2048) & 63;
                const int row0 = m0 + wm + mi * 16 + quad * 4;
                const int b = row0 >> 11;
                bf16x4 p4;
                p4[0] = (bf16)acc[mi][ni][0];
                p4[1] = (bf16)acc[mi][ni][1];
                p4[2] = (bf16)acc[mi][ni][2];
                p4[3] = (bf16)acc[mi][ni][3];
                *(bf16x4*)&Vt[((size_t)(b * 16 + h) * 64 + hs) * T_ + (row0 & 2047)] = p4;
                continue;
            }
            const float bv = BIAS ? bias[colb] : 0.f;
            for (int r = 0; r < 4; r++) {
                const int row = m0 + wm + mi * 16 + quad * 4 + r;
                float v = acc[mi][ni][r] + bv;
                if (RELU) v = fmaxf(v, 0.f);
                if (RES)  v += resid[(size_t)row * N + colb];
                if (OUTBF16) ((bf16*)Cout)[(size_t)row * N + colb] = (bf16)v;
                else         ((float*)Cout)[(size_t)row * N + colb] = v;
            }
        }
    }
}

// =====================================================================
// gemm128sk: gemm128v2 with split-K over blockIdx.z (grid z=2):
// slice z computes K/2 and plain-stores fp32 partials to Cpart+z*M*N.
// 512 blocks = 2 blocks/CU = 8 waves/CU: doubles TLP for the FF2 shape
// where full-K only fills 1 block/CU. (FF2)
// =====================================================================
__global__ __launch_bounds__(256, 2) void gemm128sk(
    const bf16* __restrict__ A, const bf16* __restrict__ Bt,
    float* __restrict__ Cpart, int M, int N, int K) {
    __shared__ __align__(16) bf16 Asub[4][128 * 32];
    __shared__ __align__(16) bf16 Bsub[4][128 * 32];
    const int tid  = threadIdx.x;
    const int lane = tid & 63, w = tid >> 6;          // 4 waves
    const int quad = lane >> 4, l15 = lane & 15;
    const int m0 = blockIdx.y * 128, n0 = blockIdx.x * 128;
    const int wm = (w & 1) * 64, wn = (w >> 1) * 64;
    const int kpb = K / (int)gridDim.z;
    const int k0  = (int)blockIdx.z * kpb;
    const int S   = kpb / 32;
    float* Cz = Cpart + (size_t)blockIdx.z * M * N;

    const int slog = (((lane & 3) ^ ((lane >> 3) & 3)) * 8);
    const int crow = lane >> 2;
    const bf16* gA0 = A  + (size_t)(m0 + 32 * w + crow)      * K + k0 + slog;
    const bf16* gA1 = A  + (size_t)(m0 + 32 * w + 16 + crow) * K + k0 + slog;
    const bf16* gB0 = Bt + (size_t)(n0 + 32 * w + crow)      * K + k0 + slog;
    const bf16* gB1 = Bt + (size_t)(n0 + 32 * w + 16 + crow) * K + k0 + slog;

    for (int t = 0; t < 3; t++) {
        gl_lds16(gA0, &Asub[t][(32 * w) * 32]);
        gl_lds16(gA1, &Asub[t][(32 * w + 16) * 32]);
        gl_lds16(gB0, &Bsub[t][(32 * w) * 32]);
        gl_lds16(gB1, &Bsub[t][(32 * w + 16) * 32]);
        gA0 += 32; gA1 += 32; gB0 += 32; gB1 += 32;
    }

    f32x4 acc[4][4];
#pragma unroll
    for (int i = 0; i < 4; i++)
#pragma unroll
        for (int j = 0; j < 4; j++) acc[i][j] = f32x4{0.f, 0.f, 0.f, 0.f};

    const int swz = (quad ^ ((l15 >> 1) & 3)) * 8;
    const int aof = (wm + l15) * 32 + swz;
    const int bof = (wn + l15) * 32 + swz;

    asm volatile("s_waitcnt vmcnt(8)" ::: "memory");
    __builtin_amdgcn_sched_barrier(0);
    __builtin_amdgcn_s_barrier();

    for (int s = 0; s < S; s++) {
        const bf16* Ab = &Asub[s & 3][0];
        const bf16* Bb = &Bsub[s & 3][0];
        const int pb = (s + 3) & 3;
        bf16x8 af[4], bfr[4];
#pragma unroll
        for (int mi = 0; mi < 4; mi++) af[mi] = *(const bf16x8*)&Ab[aof + mi * 512];
#pragma unroll
        for (int ni = 0; ni < 4; ni++) bfr[ni] = *(const bf16x8*)&Bb[bof + ni * 512];
        if (s + 3 < S) {
            gl_lds16(gA0, &Asub[pb][(32 * w) * 32]);
            gl_lds16(gA1, &Asub[pb][(32 * w + 16) * 32]);
            gl_lds16(gB0, &Bsub[pb][(32 * w) * 32]);
            gl_lds16(gB1, &Bsub[pb][(32 * w + 16) * 32]);
            gA0 += 32; gA1 += 32; gB0 += 32; gB1 += 32;
        }
        asm volatile("s_waitcnt lgkmcnt(0)" ::: "memory");
        __builtin_amdgcn_sched_barrier(0);
        __builtin_amdgcn_s_setprio(1);
#pragma unroll
        for (int mi = 0; mi < 4; mi++)
#pragma unroll
            for (int ni = 0; ni < 4; ni++)
                acc[mi][ni] = mfma16(af[mi], bfr[ni], acc[mi][ni]);
        __builtin_amdgcn_s_setprio(0);
        __builtin_amdgcn_sched_barrier(0);
        if (s <= S - 4)      asm volatile("s_waitcnt vmcnt(8)" ::: "memory");
        else if (s == S - 3) asm volatile("s_waitcnt vmcnt(4)" ::: "memory");
        else if (s == S - 2) asm volatile("s_waitcnt vmcnt(0)" ::: "memory");
        __builtin_amdgcn_s_barrier();
    }

    // ================= epilogue: fp32 plain-store partials =================
    for (int mi = 0; mi < 4; mi++) {
        for (int ni = 0; ni < 4; ni++) {
            const int colb = n0 + wn + ni * 16 + l15;
            for (int r = 0; r < 4; r++) {
                const int row = m0 + wm + mi * 16 + quad * 4 + r;
                Cz[(size_t)row * N + colb] = acc[mi][ni][r];
            }
        }
    }
}

// =====================================================================
// gemm256 v2: 256x256 tile, 512 threads (8 waves, 2M x 4N), ring-of-4
// BK=32, minimal sync. Used for FF1 (grid 256 = machine-filling).
// =====================================================================
template <int BIAS, int RELU>
__global__ __launch_bounds__(512, 2) void gemm256(
    const bf16* __restrict__ A, const bf16* __restrict__ Bt,
    const float* __restrict__ bias, void* __restrict__ Cout,
    int M, int N, int K) {
    __shared__ __align__(16) bf16 Asub[4][256 * 32];
    __shared__ __align__(16) bf16 Bsub[4][256 * 32];
    const int tid  = threadIdx.x;
    const int lane = tid & 63, w = tid >> 6;          // 8 waves
    const int wr = w >> 2, wc = w & 3;                // 2M x 4N wave grid
    const int quad = lane >> 4, l15 = lane & 15;
    const int m0 = blockIdx.y * 256, n0 = blockIdx.x * 256;
    const int S   = K / 32;

    const int slog = (((lane & 3) ^ ((lane >> 3) & 3)) * 8);
    const int crow = lane >> 2;
    const bf16* gA0 = A  + (size_t)(m0 + 32 * w + crow)      * K + slog;
    const bf16* gA1 = A  + (size_t)(m0 + 32 * w + 16 + crow) * K + slog;
    const bf16* gB0 = Bt + (size_t)(n0 + 32 * w + crow)      * K + slog;
    const bf16* gB1 = Bt + (size_t)(n0 + 32 * w + 16 + crow) * K + slog;

    for (int t = 0; t < 3; t++) {
        gl_lds16(gA0, &Asub[t][(32 * w) * 32]);
        gl_lds16(gA1, &Asub[t][(32 * w + 16) * 32]);
        gl_lds16(gB0, &Bsub[t][(32 * w) * 32]);
        gl_lds16(gB1, &Bsub[t][(32 * w + 16) * 32]);
        gA0 += 32; gA1 += 32; gB0 += 32; gB1 += 32;
    }

    f32x4 acc[8][4];
#pragma unroll
    for (int i = 0; i < 8; i++)
#pragma unroll
        for (int j = 0; j < 4; j++) acc[i][j] = f32x4{0.f, 0.f, 0.f, 0.f};

    const int swz = (quad ^ ((l15 >> 1) & 3)) * 8;
    const int aof = (wr * 128 + l15) * 32 + swz;
    const int bof = (wc * 64 + l15) * 32 + swz;

    asm volatile("s_waitcnt vmcnt(8)" ::: "memory");
    __builtin_amdgcn_sched_barrier(0);
    __builtin_amdgcn_s_barrier();

    for (int s = 0; s < S; s++) {
        const bf16* Ab = &Asub[s & 3][0];
        const bf16* Bb = &Bsub[s & 3][0];
        const int pb = (s + 3) & 3;
        bf16x8 af[4], bfr[4];
        // ---- phase A (mh=0): reads ∥ stage-A, then MFMA
#pragma unroll
        for (int f = 0; f < 4; f++) af[f] = *(const bf16x8*)&Ab[aof + f * 512];
#pragma unroll
        for (int n = 0; n < 4; n++) bfr[n] = *(const bf16x8*)&Bb[bof + n * 512];
        if (s + 3 < S) {
            gl_lds16(gA0, &Asub[pb][(32 * w) * 32]);
            gl_lds16(gA1, &Asub[pb][(32 * w + 16) * 32]);
            gA0 += 32; gA1 += 32;
        }
        asm volatile("s_waitcnt lgkmcnt(0)" ::: "memory");
        __builtin_amdgcn_sched_barrier(0);
        __builtin_amdgcn_s_setprio(1);
#pragma unroll
        for (int f = 0; f < 4; f++)
#pragma unroll
            for (int n = 0; n < 4; n++)
                acc[f][n] = mfma16(af[f], bfr[n], acc[f][n]);
        __builtin_amdgcn_s_setprio(0);
        // ---- phase B (mh=1): reads ∥ stage-B, then MFMA
#pragma unroll
        for (int f = 0; f < 4; f++) af[f] = *(const bf16x8*)&Ab[aof + 2048 + f * 512];
        if (s + 3 < S) {
            gl_lds16(gB0, &Bsub[pb][(32 * w) * 32]);
            gl_lds16(gB1, &Bsub[pb][(32 * w + 16) * 32]);
            gB0 += 32; gB1 += 32;
        }
        asm volatile("s_waitcnt lgkmcnt(0)" ::: "memory");
        __builtin_amdgcn_sched_barrier(0);
        __builtin_amdgcn_s_setprio(1);
#pragma unroll
        for (int f = 0; f < 4; f++)
#pragma unroll
            for (int n = 0; n < 4; n++)
                acc[4 + f][n] = mfma16(af[f], bfr[n], acc[4 + f][n]);
        __builtin_amdgcn_s_setprio(0);
        __builtin_amdgcn_sched_barrier(0);
        if (s <= S - 4)      asm volatile("s_waitcnt vmcnt(8)" ::: "memory");
        else if (s == S - 3) asm volatile("s_waitcnt vmcnt(4)" ::: "memory");
        else if (s == S - 2) asm volatile("s_waitcnt vmcnt(0)" ::: "memory");
        __builtin_amdgcn_s_barrier();
    }

    // ================= epilogue =================
#pragma unroll
    for (int mi = 0; mi < 8; mi++) {
#pragma unroll
        for (int ni = 0; ni < 4; ni++) {
            const int colb = n0 + wc * 64 + ni * 16 + l15;
            const int row0 = m0 + wr * 128 + (mi >> 2) * 64 + (mi & 3) * 16 + quad * 4;
            const float bv = BIAS ? bias[colb] : 0.f;
            for (int r = 0; r < 4; r++) {
                float v = acc[mi][ni][r] + bv;
                if (RELU) v = fmaxf(v, 0.f);
                ((bf16*)Cout)[(size_t)(row0 + r) * N + colb] = (bf16)v;
            }
        }
    }
}

// =====================================================================
// Flash attention v8 + packed bf16 convert (measured 48 us optimum).
// =====================================================================
#define LSTR 68
#define NJ   (T_ / 64)   // 32
__global__ __launch_bounds__(256, 2) void flash_attn(const bf16* __restrict__ QKV,
                                                     const bf16* __restrict__ Vt,
                                                     bf16* __restrict__ attn_out) {
    const int bh = blockIdx.y, b = bh >> 4, h = bh & 15;
    const int q0 = blockIdx.x * 128;
    const int tid = threadIdx.x, lane = tid & 63, w = tid >> 6;  // w in 0..3
    const int quad = lane >> 4, l15 = lane & 15;
    __shared__ __align__(16) bf16 Ks[2][64 * LSTR];
    __shared__ __align__(16) bf16 Vs[2][64 * LSTR];
    const bf16* Qb = QKV + (size_t)b * T_ * 3072 + h * 64;
    const bf16* Kb = QKV + (size_t)b * T_ * 3072 + 1024 + h * 64;
    const bf16* Vb = Vt  + (size_t)bh * HS_ * T_;

    const float sc = 0.125f * 1.44269504088896f;  // (1/sqrt(HS)) * log2(e)
    const int sr = tid >> 2, scc = (tid & 3) * 16;  // staging coords

    bf16x8 QA[2][2];
    for (int qnt = 0; qnt < 2; qnt++) {
        const size_t row = (size_t)(q0 + w * 32 + qnt * 16 + l15) * 3072;
        for (int kk = 0; kk < 2; kk++) {
            bf16x8 q = *(const bf16x8*)&Qb[row + kk * 32 + quad * 8];
            for (int i = 0; i < 8; i++) q[i] = (bf16)((float)q[i] * sc);
            QA[qnt][kk] = q;
        }
    }

    bf16x8 ones8;
    for (int i = 0; i < 8; i++) ones8[i] = (bf16)1.0f;

    f32x4 O[2][4], lacc[2];
    for (int mi = 0; mi < 2; mi++) {
        lacc[mi] = f32x4{0.f, 0.f, 0.f, 0.f};
        for (int n = 0; n < 4; n++) O[mi][n] = f32x4{0.f, 0.f, 0.f, 0.f};
    }

    *(bf16x8*)&Ks[0][sr * LSTR + scc]     = *(const bf16x8*)&Kb[(size_t)sr * 3072 + scc];
    *(bf16x8*)&Ks[0][sr * LSTR + scc + 8] = *(const bf16x8*)&Kb[(size_t)sr * 3072 + scc + 8];
    *(bf16x8*)&Vs[0][sr * LSTR + scc]     = *(const bf16x8*)&Vb[(size_t)sr * T_ + scc];
    *(bf16x8*)&Vs[0][sr * LSTR + scc + 8] = *(const bf16x8*)&Vb[(size_t)sr * T_ + scc + 8];
    __syncthreads();

    bf16x8 k0, k1, v0, v1;
    for (int j = 0; j < NJ; j++) {
        const int buf = j & 1;
        if (j + 1 < NJ) {   // prefetch next tile into registers
            const int s1 = (j + 1) * 64;
            k0 = *(const bf16x8*)&Kb[(size_t)(s1 + sr) * 3072 + scc];
            k1 = *(const bf16x8*)&Kb[(size_t)(s1 + sr) * 3072 + scc + 8];
            v0 = *(const bf16x8*)&Vb[(size_t)sr * T_ + s1 + scc];
            v1 = *(const bf16x8*)&Vb[(size_t)sr * T_ + s1 + scc + 8];
        }
        bf16x8 KB[4][2];
#pragma unroll
        for (int smt = 0; smt < 4; smt++)
#pragma unroll
            for (int kk = 0; kk < 2; kk++)
                KB[smt][kk] = *(const bf16x8*)&Ks[buf][(smt * 16 + l15) * LSTR + kk * 32 + quad * 8];

        bf16x8 PA[2][2];
#pragma unroll
        for (int qnt = 0; qnt < 2; qnt++) {
            f32x4 ST[4];
#pragma unroll
            for (int smt = 0; smt < 4; smt++) ST[smt] = f32x4{0.f, 0.f, 0.f, 0.f};
            __builtin_amdgcn_s_setprio(1);
#pragma unroll
            for (int kk = 0; kk < 2; kk++)
#pragma unroll
                for (int smt = 0; smt < 4; smt++)
                    ST[smt] = mfma16(KB[smt][kk], QA[qnt][kk], ST[smt]);
            __builtin_amdgcn_s_setprio(0);
            uint32_t w00 = pk2(__builtin_amdgcn_exp2f(ST[0][0]), __builtin_amdgcn_exp2f(ST[0][1]));
            uint32_t w01 = pk2(__builtin_amdgcn_exp2f(ST[0][2]), __builtin_amdgcn_exp2f(ST[0][3]));
            uint32_t w10 = pk2(__builtin_amdgcn_exp2f(ST[1][0]), __builtin_amdgcn_exp2f(ST[1][1]));
            uint32_t w11 = pk2(__builtin_amdgcn_exp2f(ST[1][2]), __builtin_amdgcn_exp2f(ST[1][3]));
            uint32_t w20 = pk2(__builtin_amdgcn_exp2f(ST[2][0]), __builtin_amdgcn_exp2f(ST[2][1]));
            uint32_t w21 = pk2(__builtin_amdgcn_exp2f(ST[2][2]), __builtin_amdgcn_exp2f(ST[2][3]));
            uint32_t w30 = pk2(__builtin_amdgcn_exp2f(ST[3][0]), __builtin_amdgcn_exp2f(ST[3][1]));
            uint32_t w31 = pk2(__builtin_amdgcn_exp2f(ST[3][2]), __builtin_amdgcn_exp2f(ST[3][3]));
            pl32(w00, w10); pl16(w00, w10);
            pl32(w01, w11); pl16(w01, w11);
            pl32(w20, w30); pl16(w20, w30);
            pl32(w21, w31); pl16(w21, w31);
            union { uint32_t u[4]; bf16x8 v; } pa0, pa1;
            pa0.u[0] = w00; pa0.u[1] = w01; pa0.u[2] = w10; pa0.u[3] = w11;
            pa1.u[0] = w20; pa1.u[1] = w21; pa1.u[2] = w30; pa1.u[3] = w31;
            PA[qnt][0] = pa0.v;
            PA[qnt][1] = pa1.v;
        }
        bf16x8 VB[4][2];
#pragma unroll
        for (int n = 0; n < 4; n++)
#pragma unroll
            for (int kk = 0; kk < 2; kk++)
                VB[n][kk] = *(const bf16x8*)&Vs[buf][(n * 16 + l15) * LSTR + kk * 32 + quad * 8];
        __builtin_amdgcn_s_setprio(1);
#pragma unroll
        for (int mi = 0; mi < 2; mi++) {
            const bf16x8 PA0 = PA[mi][0];
            const bf16x8 PA1 = PA[mi][1];
#pragma unroll
            for (int n = 0; n < 4; n++) {
                O[mi][n] = mfma16(PA0, VB[n][0], O[mi][n]);
                O[mi][n] = mfma16(PA1, VB[n][1], O[mi][n]);
            }
            lacc[mi] = mfma16(PA0, ones8, lacc[mi]);
            lacc[mi] = mfma16(PA1, ones8, lacc[mi]);
        }
        __builtin_amdgcn_s_setprio(0);
        if (j + 1 < NJ) {
            *(bf16x8*)&Ks[buf ^ 1][sr * LSTR + scc]     = k0;
            *(bf16x8*)&Ks[buf ^ 1][sr * LSTR + scc + 8] = k1;
            *(bf16x8*)&Vs[buf ^ 1][sr * LSTR + scc]     = v0;
            *(bf16x8*)&Vs[buf ^ 1][sr * LSTR + scc + 8] = v1;
        }
        __syncthreads();
    }

    for (int mi = 0; mi < 2; mi++) {
        for (int r = 0; r < 4; r++) {
            const float inv = 1.f / lacc[mi][r];
            const size_t tok = (size_t)b * T_ + q0 + w * 32 + mi * 16 + quad * 4 + r;
            for (int n = 0; n < 4; n++)
                attn_out[tok * 1024 + h * 64 + n * 16 + l15] = (bf16)(O[mi][n][r] * inv);
        }
    }
}

// =====================================================================
extern "C" void kernel_launch(void* const* d_in, const int* in_sizes, int n_in,
                              void* d_out, int out_size, void* d_ws, size_t ws_size,
                              hipStream_t stream) {
    const float* x   = (const float*)d_in[0];
    const float* Wq  = (const float*)d_in[1];
    const float* Wk  = (const float*)d_in[2];
    const float* Wv  = (const float*)d_in[3];
    const float* Wo  = (const float*)d_in[4];
    const float* bo  = (const float*)d_in[5];
    const float* W1  = (const float*)d_in[6];
    const float* b1  = (const float*)d_in[7];
    const float* W2  = (const float*)d_in[8];
    const float* b2  = (const float*)d_in[9];
    const float* g1  = (const float*)d_in[10];
    const float* be1 = (const float*)d_in[11];
    const float* g2  = (const float*)d_in[12];
    const float* be2 = (const float*)d_in[13];

    char* ws = (char*)d_ws;
    const size_t MB = 1ull << 20;
    bf16*  WqkvT = (bf16*)(ws);            //  6 MB  [3072][1024]
    bf16*  WoT   = (bf16*)(ws + 6  * MB);  //  2 MB  [1024][1024]
    bf16*  W1T   = (bf16*)(ws + 8  * MB);  //  8 MB  [4096][1024]
    bf16*  W2T   = (bf16*)(ws + 16 * MB);  //  8 MB  [1024][4096]
    bf16*  hbuf  = (bf16*)(ws + 24 * MB);  //  8 MB  [4096][1024]
    bf16*  QKV   = (bf16*)(ws + 32 * MB);  // 24 MB  [4096][3072]
    bf16*  Vt    = (bf16*)(ws + 56 * MB);  //  8 MB  [2048][2048]
    bf16*  attn  = (bf16*)(ws + 64 * MB);  //  8 MB  [4096][1024]
    float* x2    = (float*)(ws + 72 * MB); // 16 MB  [4096][1024]
    bf16*  ff1   = (bf16*)(ws + 32 * MB);  // 32 MB  [4096][4096] (reuses QKV+Vt)
    float* part  = (float*)(ws + 88 * MB); // 32 MB  [2][4096][1024] FF2 partials
    float* out   = (float*)d_out;

    // weight prep + ln1 in ONE launch
    prep_fused<<<16384, 256, 0, stream>>>(Wq, Wk, Wv, Wo, W1, W2, x, g1, be1,
                                          WqkvT, WoT, W1T, W2T, hbuf);
    // QKV = h @ WqkvT^T (minimal-sync 128^2, 768 blocks);
    // V region written transposed into Vt
    gemm128v2<0, 0, 0, 1, 1><<<dim3(24, 32), 256, 0, stream>>>(
        hbuf, WqkvT, nullptr, nullptr, QKV, Vt, NTOK, 3072, 1024);
    // flash attention (v8 + cvt_pk) -> attn [4096][1024]
    flash_attn<<<dim3(T_ / 128, B_ * H_), 256, 0, stream>>>(QKV, Vt, attn);
    // x2 = x + attn @ Wo + bo   (fused, fp32)
    gemm128v2<1, 0, 1, 0><<<dim3(8, 32), 256, 0, stream>>>(
        attn, WoT, bo, x, x2, nullptr, NTOK, 1024, 1024);
    // ln2 -> h
    ln_kernel<<<NTOK, 256, 0, stream>>>(x2, g2, be2, hbuf);
    // ff1 = relu(h @ W1 + b1)  bf16 [4096][4096]
    gemm256<1, 1><<<dim3(16, 16), 512, 0, stream>>>(
        hbuf, W1T, b1, ff1, NTOK, 4096, 1024);
    // FF2 split-K=2 (512 blocks = 2/CU), then combine: out = p0+p1+x2+b2
    gemm128sk<<<dim3(8, 32, 2), 256, 0, stream>>>(
        ff1, W2T, part, NTOK, 1024, 4096);
    combine2<<<NTOK, 256, 0, stream>>>(part, part + (size_t)NTOK * 1024,
                                       x2, b2, out);
}

// Round 13
// 304.663 us; speedup vs baseline: 1.0531x; 1.0531x over previous
//
#include <hip/hip_runtime.h>
#include <cstdint>
#include <cmath>

typedef __bf16 bf16;
typedef __bf16 bf16x8 __attribute__((ext_vector_type(8)));
typedef __bf16 bf16x4 __attribute__((ext_vector_type(4)));
typedef __bf16 bf16x2 __attribute__((ext_vector_type(2)));
typedef float  f32x4  __attribute__((ext_vector_type(4)));

#define B_   2
#define T_   2048
#define D_   1024
#define H_   16
#define HS_  64
#define NTOK (B_ * T_)   // 4096

// ---- async global->LDS, 16B per lane. LDS dest = wave-uniform base + lane*16.
typedef __attribute__((address_space(1))) uint8_t* gp1_t;
typedef __attribute__((address_space(3))) uint8_t* lp3_t;
__device__ __forceinline__ void gl_lds16(const void* g, void* l) {
    __builtin_amdgcn_global_load_lds((gp1_t)(uintptr_t)g,
                                     (lp3_t)(uint32_t)(uintptr_t)l,
                                     16, 0, 0);
}

__device__ __forceinline__ f32x4 mfma16(bf16x8 a, bf16x8 b, f32x4 c) {
    return __builtin_amdgcn_mfma_f32_16x16x32_bf16(a, b, c, 0, 0, 0);
}

// pack two f32 -> one dword of 2 bf16 via the HW packed convert
__device__ __forceinline__ uint32_t pk2(float lo, float hi) {
    uint32_t r;
    asm("v_cvt_pk_bf16_f32 %0, %1, %2" : "=v"(r) : "v"(lo), "v"(hi));
    return r;
}
// gfx950 two-register lane swaps: a[32:63] <-> b[0:31]
__device__ __forceinline__ void pl32(uint32_t& a, uint32_t& b) {
    asm("v_permlane32_swap_b32 %0, %1" : "+v"(a), "+v"(b));
}
// a[16:31] <-> b[0:15], a[48:63] <-> b[32:47]
__device__ __forceinline__ void pl16(uint32_t& a, uint32_t& b) {
    asm("v_permlane16_swap_b32 %0, %1" : "+v"(a), "+v"(b));
}

// =====================================================================
// prep_fused: ONE launch for all weight prep + ln1.
// =====================================================================
__global__ __launch_bounds__(256) void prep_fused(
    const float* __restrict__ Wq, const float* __restrict__ Wk,
    const float* __restrict__ Wv, const float* __restrict__ Wo,
    const float* __restrict__ W1, const float* __restrict__ W2,
    const float* __restrict__ x,  const float* __restrict__ g,
    const float* __restrict__ be,
    bf16* __restrict__ WqkvT, bf16* __restrict__ WoT,
    bf16* __restrict__ W1T,  bf16* __restrict__ W2T,
    bf16* __restrict__ hbuf) {
    const int bid = blockIdx.x;
    const int tid = threadIdx.x;

    if (bid >= 12288) {
        // ---------------- ln1: one row ----------------
        const int row = bid - 12288;
        const float4 v = ((const float4*)(x + (size_t)row * 1024))[tid];
        float s  = v.x + v.y + v.z + v.w;
        float s2 = v.x * v.x + v.y * v.y + v.z * v.z + v.w * v.w;
        for (int m = 1; m < 64; m <<= 1) {
            s  += __shfl_xor(s, m);
            s2 += __shfl_xor(s2, m);
        }
        __shared__ float rs[4], rq[4];
        const int lane = tid & 63, wv = tid >> 6;
        if (lane == 0) { rs[wv] = s; rq[wv] = s2; }
        __syncthreads();
        s  = rs[0] + rs[1] + rs[2] + rs[3];
        s2 = rq[0] + rq[1] + rq[2] + rq[3];
        const float mu   = s * (1.f / 1024.f);
        const float var  = s2 * (1.f / 1024.f) - mu * mu;
        const float rstd = rsqrtf(var + 1e-5f);
        const float4 gg = ((const float4*)g)[tid];
        const float4 bb = ((const float4*)be)[tid];
        bf16x4 o;
        o[0] = (bf16)((v.x - mu) * rstd * gg.x + bb.x);
        o[1] = (bf16)((v.y - mu) * rstd * gg.y + bb.y);
        o[2] = (bf16)((v.z - mu) * rstd * gg.z + bb.z);
        o[3] = (bf16)((v.w - mu) * rstd * gg.w + bb.w);
        *(bf16x4*)(hbuf + (size_t)row * 1024 + tid * 4) = o;
        return;
    }

    // ---------------- transpose-cast regions ----------------
    const float* in; bf16* out;
    int C, R, bx, by;
    if (bid < 3072) {              // qkv_pack: z-th head, R=1024, C=64
        const int z = bid >> 6, rem = bid & 63;
        bx = rem & 1; by = rem >> 1;
        C = HS_; R = D_;
        in  = (z < 16 ? Wq : z < 32 ? Wk : Wv) + (size_t)(z & 15) * D_ * HS_;
        out = WqkvT + (size_t)z * HS_ * D_;
    } else if (bid < 4096) {       // Wo: R=1024, C=1024
        const int rem = bid - 3072;
        bx = rem & 31; by = rem >> 5;
        C = 1024; R = 1024; in = Wo; out = WoT;
    } else if (bid < 8192) {       // W1: R=1024, C=4096
        const int rem = bid - 4096;
        bx = rem & 127; by = rem >> 7;
        C = 4096; R = 1024; in = W1; out = W1T;
    } else {                       // W2: R=4096, C=1024
        const int rem = bid - 8192;
        bx = rem & 31; by = rem >> 5;
        C = 1024; R = 4096; in = W2; out = W2T;
    }
    const int tx = tid & 31, ty = tid >> 5;
    const int c0 = bx * 32, r0 = by * 32;
    __shared__ float t[32][33];
    for (int i = 0; i < 4; i++) {
        int r = ty + i * 8;
        t[r][tx] = in[(size_t)(r0 + r) * C + c0 + tx];
    }
    __syncthreads();
    for (int i = 0; i < 4; i++) {
        int rr = ty + i * 8;
        out[(size_t)(c0 + rr) * R + r0 + tx] = (bf16)t[tx][rr];
    }
}

// =====================================================================
// LayerNorm: x [4096][1024] fp32 -> out bf16, one block per row (ln2)
// =====================================================================
__global__ __launch_bounds__(256) void ln_kernel(const float* __restrict__ x,
                                                 const float* __restrict__ g,
                                                 const float* __restrict__ b,
                                                 bf16* __restrict__ out) {
    const int row = blockIdx.x;
    const int tid = threadIdx.x;
    const float4 v = ((const float4*)(x + (size_t)row * 1024))[tid];
    float s  = v.x + v.y + v.z + v.w;
    float s2 = v.x * v.x + v.y * v.y + v.z * v.z + v.w * v.w;
    for (int m = 1; m < 64; m <<= 1) {
        s  += __shfl_xor(s, m);
        s2 += __shfl_xor(s2, m);
    }
    __shared__ float rs[4], rq[4];
    const int lane = tid & 63, wv = tid >> 6;
    if (lane == 0) { rs[wv] = s; rq[wv] = s2; }
    __syncthreads();
    s  = rs[0] + rs[1] + rs[2] + rs[3];
    s2 = rq[0] + rq[1] + rq[2] + rq[3];
    const float mu   = s * (1.f / 1024.f);
    const float var  = s2 * (1.f / 1024.f) - mu * mu;
    const float rstd = rsqrtf(var + 1e-5f);
    const float4 gg = ((const float4*)g)[tid];
    const float4 bb = ((const float4*)b)[tid];
    bf16x4 o;
    o[0] = (bf16)((v.x - mu) * rstd * gg.x + bb.x);
    o[1] = (bf16)((v.y - mu) * rstd * gg.y + bb.y);
    o[2] = (bf16)((v.z - mu) * rstd * gg.z + bb.z);
    o[3] = (bf16)((v.w - mu) * rstd * gg.w + bb.w);
    *(bf16x4*)(out + (size_t)row * 1024 + tid * 4) = o;
}

// =====================================================================
// gemm128v2: 128x128 tile, 256 threads (4 waves, 2M x 2N), minimal-sync
// ring-of-4 BK=32 subtile pipeline with counted vmcnt. 64 KB LDS ->
// 2 blocks/CU.
// SWZ8: XCD-aware remap for gridDim.x==8 grids. Default dispatch puts
// the 8 n-blocks sharing an A panel on 8 DIFFERENT XCDs (l=x+8y,
// xcd=l%8=x) -> A panel filled into 8 L2s (measured FETCH 143MB vs 56
// ideal). Remap x=idx&7, y=xcd*4+(idx>>3): A panel confined to one XCD.
// =====================================================================
template <int BIAS, int RELU, int RES, int OUTBF16, int VTP = 0, int SWZ8 = 0>
__global__ __launch_bounds__(256, 2) void gemm128v2(
    const bf16* __restrict__ A, const bf16* __restrict__ Bt,
    const float* __restrict__ bias, const float* __restrict__ resid,
    void* __restrict__ Cout, bf16* __restrict__ Vt, int M, int N, int K) {
    __shared__ __align__(16) bf16 Asub[4][128 * 32];
    __shared__ __align__(16) bf16 Bsub[4][128 * 32];
    const int tid  = threadIdx.x;
    const int lane = tid & 63, w = tid >> 6;          // 4 waves
    const int quad = lane >> 4, l15 = lane & 15;
    int bxx = blockIdx.x, byy = blockIdx.y;
    if (SWZ8) {   // bijective XCD remap (requires gridDim.x == 8)
        const int l = bxx + (byy << 3);
        const int xcd = l & 7, idx = l >> 3;          // idx in [0, gridDim.y)
        bxx = idx & 7;
        byy = xcd * (gridDim.y >> 3) + (idx >> 3);
    }
    const int m0 = byy * 128, n0 = bxx * 128;
    const int wm = (w & 1) * 64, wn = (w >> 1) * 64;
    const int S  = K / 32;

    const int slog = (((lane & 3) ^ ((lane >> 3) & 3)) * 8);
    const int crow = lane >> 2;
    const bf16* gA0 = A  + (size_t)(m0 + 32 * w + crow)      * K + slog;
    const bf16* gA1 = A  + (size_t)(m0 + 32 * w + 16 + crow) * K + slog;
    const bf16* gB0 = Bt + (size_t)(n0 + 32 * w + crow)      * K + slog;
    const bf16* gB1 = Bt + (size_t)(n0 + 32 * w + 16 + crow) * K + slog;

    for (int t = 0; t < 3; t++) {
        gl_lds16(gA0, &Asub[t][(32 * w) * 32]);
        gl_lds16(gA1, &Asub[t][(32 * w + 16) * 32]);
        gl_lds16(gB0, &Bsub[t][(32 * w) * 32]);
        gl_lds16(gB1, &Bsub[t][(32 * w + 16) * 32]);
        gA0 += 32; gA1 += 32; gB0 += 32; gB1 += 32;
    }

    f32x4 acc[4][4];
#pragma unroll
    for (int i = 0; i < 4; i++)
#pragma unroll
        for (int j = 0; j < 4; j++) acc[i][j] = f32x4{0.f, 0.f, 0.f, 0.f};

    const int swz = (quad ^ ((l15 >> 1) & 3)) * 8;
    const int aof = (wm + l15) * 32 + swz;   // + mi*512
    const int bof = (wn + l15) * 32 + swz;   // + ni*512

    asm volatile("s_waitcnt vmcnt(8)" ::: "memory");   // subtile 0 landed
    __builtin_amdgcn_sched_barrier(0);
    __builtin_amdgcn_s_barrier();

    for (int s = 0; s < S; s++) {
        const bf16* Ab = &Asub[s & 3][0];
        const bf16* Bb = &Bsub[s & 3][0];
        const int pb = (s + 3) & 3;
        bf16x8 af[4], bfr[4];
#pragma unroll
        for (int mi = 0; mi < 4; mi++) af[mi] = *(const bf16x8*)&Ab[aof + mi * 512];
#pragma unroll
        for (int ni = 0; ni < 4; ni++) bfr[ni] = *(const bf16x8*)&Bb[bof + ni * 512];
        if (s + 3 < S) {
            gl_lds16(gA0, &Asub[pb][(32 * w) * 32]);
            gl_lds16(gA1, &Asub[pb][(32 * w + 16) * 32]);
            gl_lds16(gB0, &Bsub[pb][(32 * w) * 32]);
            gl_lds16(gB1, &Bsub[pb][(32 * w + 16) * 32]);
            gA0 += 32; gA1 += 32; gB0 += 32; gB1 += 32;
        }
        asm volatile("s_waitcnt lgkmcnt(0)" ::: "memory");
        __builtin_amdgcn_sched_barrier(0);
        __builtin_amdgcn_s_setprio(1);
#pragma unroll
        for (int mi = 0; mi < 4; mi++)
#pragma unroll
            for (int ni = 0; ni < 4; ni++)
                acc[mi][ni] = mfma16(af[mi], bfr[ni], acc[mi][ni]);
        __builtin_amdgcn_s_setprio(0);
        __builtin_amdgcn_sched_barrier(0);
        if (s <= S - 4)      asm volatile("s_waitcnt vmcnt(8)" ::: "memory");
        else if (s == S - 3) asm volatile("s_waitcnt vmcnt(4)" ::: "memory");
        else if (s == S - 2) asm volatile("s_waitcnt vmcnt(0)" ::: "memory");
        __builtin_amdgcn_s_barrier();
    }

    // ================= epilogue =================
    for (int mi = 0; mi < 4; mi++) {
        for (int ni = 0; ni < 4; ni++) {
            const int colb = n0 + wn + ni * 16 + l15;
            if (VTP && colb >= 2048) {
                const int h = (colb - 2048) >> 6, hs = (colb - 2048) & 63;
                const int row0 = m0 + wm + mi * 16 + quad * 4;
                const int b = row0 >> 11;
                bf16x4 p4;
                p4[0] = (bf16)acc[mi][ni][0];
                p4[1] = (bf16)acc[mi][ni][1];
                p4[2] = (bf16)acc[mi][ni][2];
                p4[3] = (bf16)acc[mi][ni][3];
                *(bf16x4*)&Vt[((size_t)(b * 16 + h) * 64 + hs) * T_ + (row0 & 2047)] = p4;
                continue;
            }
            const float bv = BIAS ? bias[colb] : 0.f;
            for (int r = 0; r < 4; r++) {
                const int row = m0 + wm + mi * 16 + quad * 4 + r;
                float v = acc[mi][ni][r] + bv;
                if (RELU) v = fmaxf(v, 0.f);
                if (RES)  v += resid[(size_t)row * N + colb];
                if (OUTBF16) ((bf16*)Cout)[(size_t)row * N + colb] = (bf16)v;
                else         ((float*)Cout)[(size_t)row * N + colb] = v;
            }
        }
    }
}

// =====================================================================
// gemm256 v2: 256x256 tile, 512 threads (8 waves, 2M x 4N), ring-of-4
// BK=32, minimal sync. FF1: grid (16,16).
// SWZ16: balanced 2x4 XCD split for 16x16 grids (A and B both 8 MB):
// x = (xcd&1)*8 + (idx&7), y = (xcd>>1)*4 + (idx>>3)  -> A filled into
// 2 L2s, B into 4 (72 -> 48 MB fill traffic).
// =====================================================================
template <int BIAS, int RELU, int SWZ16 = 0>
__global__ __launch_bounds__(512, 2) void gemm256(
    const bf16* __restrict__ A, const bf16* __restrict__ Bt,
    const float* __restrict__ bias, void* __restrict__ Cout,
    int M, int N, int K) {
    __shared__ __align__(16) bf16 Asub[4][256 * 32];
    __shared__ __align__(16) bf16 Bsub[4][256 * 32];
    const int tid  = threadIdx.x;
    const int lane = tid & 63, w = tid >> 6;          // 8 waves
    const int wr = w >> 2, wc = w & 3;                // 2M x 4N wave grid
    const int quad = lane >> 4, l15 = lane & 15;
    int bxx = blockIdx.x, byy = blockIdx.y;
    if (SWZ16) {  // bijective XCD remap (requires 16x16 grid)
        const int l = bxx + (byy << 4);
        const int xcd = l & 7, idx = l >> 3;          // idx in [0,32)
        bxx = (xcd & 1) * 8 + (idx & 7);
        byy = (xcd >> 1) * 4 + (idx >> 3);
    }
    const int m0 = byy * 256, n0 = bxx * 256;
    const int S   = K / 32;

    const int slog = (((lane & 3) ^ ((lane >> 3) & 3)) * 8);
    const int crow = lane >> 2;
    const bf16* gA0 = A  + (size_t)(m0 + 32 * w + crow)      * K + slog;
    const bf16* gA1 = A  + (size_t)(m0 + 32 * w + 16 + crow) * K + slog;
    const bf16* gB0 = Bt + (size_t)(n0 + 32 * w + crow)      * K + slog;
    const bf16* gB1 = Bt + (size_t)(n0 + 32 * w + 16 + crow) * K + slog;

    for (int t = 0; t < 3; t++) {
        gl_lds16(gA0, &Asub[t][(32 * w) * 32]);
        gl_lds16(gA1, &Asub[t][(32 * w + 16) * 32]);
        gl_lds16(gB0, &Bsub[t][(32 * w) * 32]);
        gl_lds16(gB1, &Bsub[t][(32 * w + 16) * 32]);
        gA0 += 32; gA1 += 32; gB0 += 32; gB1 += 32;
    }

    f32x4 acc[8][4];
#pragma unroll
    for (int i = 0; i < 8; i++)
#pragma unroll
        for (int j = 0; j < 4; j++) acc[i][j] = f32x4{0.f, 0.f, 0.f, 0.f};

    const int swz = (quad ^ ((l15 >> 1) & 3)) * 8;
    const int aof = (wr * 128 + l15) * 32 + swz;
    const int bof = (wc * 64 + l15) * 32 + swz;

    asm volatile("s_waitcnt vmcnt(8)" ::: "memory");
    __builtin_amdgcn_sched_barrier(0);
    __builtin_amdgcn_s_barrier();

    for (int s = 0; s < S; s++) {
        const bf16* Ab = &Asub[s & 3][0];
        const bf16* Bb = &Bsub[s & 3][0];
        const int pb = (s + 3) & 3;
        bf16x8 af[4], bfr[4];
        // ---- phase A (mh=0): reads ∥ stage-A, then MFMA
#pragma unroll
        for (int f = 0; f < 4; f++) af[f] = *(const bf16x8*)&Ab[aof + f * 512];
#pragma unroll
        for (int n = 0; n < 4; n++) bfr[n] = *(const bf16x8*)&Bb[bof + n * 512];
        if (s + 3 < S) {
            gl_lds16(gA0, &Asub[pb][(32 * w) * 32]);
            gl_lds16(gA1, &Asub[pb][(32 * w + 16) * 32]);
            gA0 += 32; gA1 += 32;
        }
        asm volatile("s_waitcnt lgkmcnt(0)" ::: "memory");
        __builtin_amdgcn_sched_barrier(0);
        __builtin_amdgcn_s_setprio(1);
#pragma unroll
        for (int f = 0; f < 4; f++)
#pragma unroll
            for (int n = 0; n < 4; n++)
                acc[f][n] = mfma16(af[f], bfr[n], acc[f][n]);
        __builtin_amdgcn_s_setprio(0);
        // ---- phase B (mh=1): reads ∥ stage-B, then MFMA
#pragma unroll
        for (int f = 0; f < 4; f++) af[f] = *(const bf16x8*)&Ab[aof + 2048 + f * 512];
        if (s + 3 < S) {
            gl_lds16(gB0, &Bsub[pb][(32 * w) * 32]);
            gl_lds16(gB1, &Bsub[pb][(32 * w + 16) * 32]);
            gB0 += 32; gB1 += 32;
        }
        asm volatile("s_waitcnt lgkmcnt(0)" ::: "memory");
        __builtin_amdgcn_sched_barrier(0);
        __builtin_amdgcn_s_setprio(1);
#pragma unroll
        for (int f = 0; f < 4; f++)
#pragma unroll
            for (int n = 0; n < 4; n++)
                acc[4 + f][n] = mfma16(af[f], bfr[n], acc[4 + f][n]);
        __builtin_amdgcn_s_setprio(0);
        __builtin_amdgcn_sched_barrier(0);
        if (s <= S - 4)      asm volatile("s_waitcnt vmcnt(8)" ::: "memory");
        else if (s == S - 3) asm volatile("s_waitcnt vmcnt(4)" ::: "memory");
        else if (s == S - 2) asm volatile("s_waitcnt vmcnt(0)" ::: "memory");
        __builtin_amdgcn_s_barrier();
    }

    // ================= epilogue =================
#pragma unroll
    for (int mi = 0; mi < 8; mi++) {
#pragma unroll
        for (int ni = 0; ni < 4; ni++) {
            const int colb = n0 + wc * 64 + ni * 16 + l15;
            const int row0 = m0 + wr * 128 + (mi >> 2) * 64 + (mi & 3) * 16 + quad * 4;
            const float bv = BIAS ? bias[colb] : 0.f;
            for (int r = 0; r < 4; r++) {
                float v = acc[mi][ni][r] + bv;
                if (RELU) v = fmaxf(v, 0.f);
                ((bf16*)Cout)[(size_t)(row0 + r) * N + colb] = (bf16)v;
            }
        }
    }
}

// =====================================================================
// Flash attention v8 + packed bf16 convert (measured 48 us optimum).
// =====================================================================
#define LSTR 68
#define NJ   (T_ / 64)   // 32
__global__ __launch_bounds__(256, 2) void flash_attn(const bf16* __restrict__ QKV,
                                                     const bf16* __restrict__ Vt,
                                                     bf16* __restrict__ attn_out) {
    const int bh = blockIdx.y, b = bh >> 4, h = bh & 15;
    const int q0 = blockIdx.x * 128;
    const int tid = threadIdx.x, lane = tid & 63, w = tid >> 6;  // w in 0..3
    const int quad = lane >> 4, l15 = lane & 15;
    __shared__ __align__(16) bf16 Ks[2][64 * LSTR];
    __shared__ __align__(16) bf16 Vs[2][64 * LSTR];
    const bf16* Qb = QKV + (size_t)b * T_ * 3072 + h * 64;
    const bf16* Kb = QKV + (size_t)b * T_ * 3072 + 1024 + h * 64;
    const bf16* Vb = Vt  + (size_t)bh * HS_ * T_;

    const float sc = 0.125f * 1.44269504088896f;  // (1/sqrt(HS)) * log2(e)
    const int sr = tid >> 2, scc = (tid & 3) * 16;  // staging coords

    bf16x8 QA[2][2];
    for (int qnt = 0; qnt < 2; qnt++) {
        const size_t row = (size_t)(q0 + w * 32 + qnt * 16 + l15) * 3072;
        for (int kk = 0; kk < 2; kk++) {
            bf16x8 q = *(const bf16x8*)&Qb[row + kk * 32 + quad * 8];
            for (int i = 0; i < 8; i++) q[i] = (bf16)((float)q[i] * sc);
            QA[qnt][kk] = q;
        }
    }

    bf16x8 ones8;
    for (int i = 0; i < 8; i++) ones8[i] = (bf16)1.0f;

    f32x4 O[2][4], lacc[2];
    for (int mi = 0; mi < 2; mi++) {
        lacc[mi] = f32x4{0.f, 0.f, 0.f, 0.f};
        for (int n = 0; n < 4; n++) O[mi][n] = f32x4{0.f, 0.f, 0.f, 0.f};
    }

    *(bf16x8*)&Ks[0][sr * LSTR + scc]     = *(const bf16x8*)&Kb[(size_t)sr * 3072 + scc];
    *(bf16x8*)&Ks[0][sr * LSTR + scc + 8] = *(const bf16x8*)&Kb[(size_t)sr * 3072 + scc + 8];
    *(bf16x8*)&Vs[0][sr * LSTR + scc]     = *(const bf16x8*)&Vb[(size_t)sr * T_ + scc];
    *(bf16x8*)&Vs[0][sr * LSTR + scc + 8] = *(const bf16x8*)&Vb[(size_t)sr * T_ + scc + 8];
    __syncthreads();

    bf16x8 k0, k1, v0, v1;
    for (int j = 0; j < NJ; j++) {
        const int buf = j & 1;
        if (j + 1 < NJ) {   // prefetch next tile into registers
            const int s1 = (j + 1) * 64;
            k0 = *(const bf16x8*)&Kb[(size_t)(s1 + sr) * 3072 + scc];
            k1 = *(const bf16x8*)&Kb[(size_t)(s1 + sr) * 3072 + scc + 8];
            v0 = *(const bf16x8*)&Vb[(size_t)sr * T_ + s1 + scc];
            v1 = *(const bf16x8*)&Vb[(size_t)sr * T_ + s1 + scc + 8];
        }
        bf16x8 KB[4][2];
#pragma unroll
        for (int smt = 0; smt < 4; smt++)
#pragma unroll
            for (int kk = 0; kk < 2; kk++)
                KB[smt][kk] = *(const bf16x8*)&Ks[buf][(smt * 16 + l15) * LSTR + kk * 32 + quad * 8];

        bf16x8 PA[2][2];
#pragma unroll
        for (int qnt = 0; qnt < 2; qnt++) {
            f32x4 ST[4];
#pragma unroll
            for (int smt = 0; smt < 4; smt++) ST[smt] = f32x4{0.f, 0.f, 0.f, 0.f};
            __builtin_amdgcn_s_setprio(1);
#pragma unroll
            for (int kk = 0; kk < 2; kk++)
#pragma unroll
                for (int smt = 0; smt < 4; smt++)
                    ST[smt] = mfma16(KB[smt][kk], QA[qnt][kk], ST[smt]);
            __builtin_amdgcn_s_setprio(0);
            uint32_t w00 = pk2(__builtin_amdgcn_exp2f(ST[0][0]), __builtin_amdgcn_exp2f(ST[0][1]));
            uint32_t w01 = pk2(__builtin_amdgcn_exp2f(ST[0][2]), __builtin_amdgcn_exp2f(ST[0][3]));
            uint32_t w10 = pk2(__builtin_amdgcn_exp2f(ST[1][0]), __builtin_amdgcn_exp2f(ST[1][1]));
            uint32_t w11 = pk2(__builtin_amdgcn_exp2f(ST[1][2]), __builtin_amdgcn_exp2f(ST[1][3]));
            uint32_t w20 = pk2(__builtin_amdgcn_exp2f(ST[2][0]), __builtin_amdgcn_exp2f(ST[2][1]));
            uint32_t w21 = pk2(__builtin_amdgcn_exp2f(ST[2][2]), __builtin_amdgcn_exp2f(ST[2][3]));
            uint32_t w30 = pk2(__builtin_amdgcn_exp2f(ST[3][0]), __builtin_amdgcn_exp2f(ST[3][1]));
            uint32_t w31 = pk2(__builtin_amdgcn_exp2f(ST[3][2]), __builtin_amdgcn_exp2f(ST[3][3]));
            pl32(w00, w10); pl16(w00, w10);
            pl32(w01, w11); pl16(w01, w11);
            pl32(w20, w30); pl16(w20, w30);
            pl32(w21, w31); pl16(w21, w31);
            union { uint32_t u[4]; bf16x8 v; } pa0, pa1;
            pa0.u[0] = w00; pa0.u[1] = w01; pa0.u[2] = w10; pa0.u[3] = w11;
            pa1.u[0] = w20; pa1.u[1] = w21; pa1.u[2] = w30; pa1.u[3] = w31;
            PA[qnt][0] = pa0.v;
            PA[qnt][1] = pa1.v;
        }
        bf16x8 VB[4][2];
#pragma unroll
        for (int n = 0; n < 4; n++)
#pragma unroll
            for (int kk = 0; kk < 2; kk++)
                VB[n][kk] = *(const bf16x8*)&Vs[buf][(n * 16 + l15) * LSTR + kk * 32 + quad * 8];
        __builtin_amdgcn_s_setprio(1);
#pragma unroll
        for (int mi = 0; mi < 2; mi++) {
            const bf16x8 PA0 = PA[mi][0];
            const bf16x8 PA1 = PA[mi][1];
#pragma unroll
            for (int n = 0; n < 4; n++) {
                O[mi][n] = mfma16(PA0, VB[n][0], O[mi][n]);
                O[mi][n] = mfma16(PA1, VB[n][1], O[mi][n]);
            }
            lacc[mi] = mfma16(PA0, ones8, lacc[mi]);
            lacc[mi] = mfma16(PA1, ones8, lacc[mi]);
        }
        __builtin_amdgcn_s_setprio(0);
        if (j + 1 < NJ) {
            *(bf16x8*)&Ks[buf ^ 1][sr * LSTR + scc]     = k0;
            *(bf16x8*)&Ks[buf ^ 1][sr * LSTR + scc + 8] = k1;
            *(bf16x8*)&Vs[buf ^ 1][sr * LSTR + scc]     = v0;
            *(bf16x8*)&Vs[buf ^ 1][sr * LSTR + scc + 8] = v1;
        }
        __syncthreads();
    }

    for (int mi = 0; mi < 2; mi++) {
        for (int r = 0; r < 4; r++) {
            const float inv = 1.f / lacc[mi][r];
            const size_t tok = (size_t)b * T_ + q0 + w * 32 + mi * 16 + quad * 4 + r;
            for (int n = 0; n < 4; n++)
                attn_out[tok * 1024 + h * 64 + n * 16 + l15] = (bf16)(O[mi][n][r] * inv);
        }
    }
}

// =====================================================================
extern "C" void kernel_launch(void* const* d_in, const int* in_sizes, int n_in,
                              void* d_out, int out_size, void* d_ws, size_t ws_size,
                              hipStream_t stream) {
    const float* x   = (const float*)d_in[0];
    const float* Wq  = (const float*)d_in[1];
    const float* Wk  = (const float*)d_in[2];
    const float* Wv  = (const float*)d_in[3];
    const float* Wo  = (const float*)d_in[4];
    const float* bo  = (const float*)d_in[5];
    const float* W1  = (const float*)d_in[6];
    const float* b1  = (const float*)d_in[7];
    const float* W2  = (const float*)d_in[8];
    const float* b2  = (const float*)d_in[9];
    const float* g1  = (const float*)d_in[10];
    const float* be1 = (const float*)d_in[11];
    const float* g2  = (const float*)d_in[12];
    const float* be2 = (const float*)d_in[13];

    char* ws = (char*)d_ws;
    const size_t MB = 1ull << 20;
    bf16*  WqkvT = (bf16*)(ws);            //  6 MB  [3072][1024]
    bf16*  WoT   = (bf16*)(ws + 6  * MB);  //  2 MB  [1024][1024]
    bf16*  W1T   = (bf16*)(ws + 8  * MB);  //  8 MB  [4096][1024]
    bf16*  W2T   = (bf16*)(ws + 16 * MB);  //  8 MB  [1024][4096]
    bf16*  hbuf  = (bf16*)(ws + 24 * MB);  //  8 MB  [4096][1024]
    bf16*  QKV   = (bf16*)(ws + 32 * MB);  // 24 MB  [4096][3072]
    bf16*  Vt    = (bf16*)(ws + 56 * MB);  //  8 MB  [2048][2048]
    bf16*  attn  = (bf16*)(ws + 64 * MB);  //  8 MB  [4096][1024]
    float* x2    = (float*)(ws + 72 * MB); // 16 MB  [4096][1024]
    bf16*  ff1   = (bf16*)(ws + 32 * MB);  // 32 MB  [4096][4096] (reuses QKV+Vt)
    float* out   = (float*)d_out;

    // weight prep + ln1 in ONE launch
    prep_fused<<<16384, 256, 0, stream>>>(Wq, Wk, Wv, Wo, W1, W2, x, g1, be1,
                                          WqkvT, WoT, W1T, W2T, hbuf);
    // QKV = h @ WqkvT^T (minimal-sync 128^2, 768 blocks);
    // V region written transposed into Vt
    gemm128v2<0, 0, 0, 1, 1, 0><<<dim3(24, 32), 256, 0, stream>>>(
        hbuf, WqkvT, nullptr, nullptr, QKV, Vt, NTOK, 3072, 1024);
    // flash attention (v8 + cvt_pk) -> attn [4096][1024]
    flash_attn<<<dim3(T_ / 128, B_ * H_), 256, 0, stream>>>(QKV, Vt, attn);
    // x2 = x + attn @ Wo + bo   (fused, fp32; XCD-swizzled)
    gemm128v2<1, 0, 1, 0, 0, 1><<<dim3(8, 32), 256, 0, stream>>>(
        attn, WoT, bo, x, x2, nullptr, NTOK, 1024, 1024);
    // ln2 -> h
    ln_kernel<<<NTOK, 256, 0, stream>>>(x2, g2, be2, hbuf);
    // ff1 = relu(h @ W1 + b1)  bf16 [4096][4096]  (XCD-swizzled 2x4)
    gemm256<1, 1, 1><<<dim3(16, 16), 512, 0, stream>>>(
        hbuf, W1T, b1, ff1, NTOK, 4096, 1024);
    // out = x2 + ff1 @ W2 + b2  (full K=4096, fused; XCD-swizzled)
    gemm128v2<1, 0, 1, 0, 0, 1><<<dim3(8, 32), 256, 0, stream>>>(
        ff1, W2T, b2, x2, out, nullptr, NTOK, 1024, 4096);
}